// Round 6
// baseline (256.225 us; speedup 1.0000x reference)
//
#include <hip/hip_runtime.h>

// OHEM loss, specialized for NUM_CLASSES == 1:
//   ce = logsumexp(cls_preds, axis=2) - cls_preds[...,0] == 0 exactly,
//   so cls_loss == 0 and hard-negative mining is dead code.
//   out = 0.2 * sum_{pos} smooth_l1(loc_preds - loc_targets) / num_pos
//
// Round 5: rounds 1-2 both ~80us at 2.7 TB/s effective with lane-strided
// loads (32B/64B stride between lanes -> 32-64 cache lines per load instr).
// This round: UNIT-STRIDE lanes. One thread = one float4; a wave's load is
// 64 lanes x 16B = 1 KiB contiguous (16 lines/instr, the 6.3 TB/s pattern).
// Mask comes from cls_t[j>>1] (2-lane broadcast); anchors counted once.

constexpr int BLK = 256;

__device__ __forceinline__ float sl1(float d) {
    float ax = fabsf(d);
    return (ax < 1.0f) ? 0.5f * d * d : ax - 0.5f;
}

__global__ __launch_bounds__(BLK) void ohem_partial(
        const float4* __restrict__ p4,     // [n_vec] = [B*A*2] float4
        const float4* __restrict__ t4,     // [n_vec]
        const int*    __restrict__ cls,    // [B*A]
        double* __restrict__ part_sum,
        int*    __restrict__ part_cnt,
        int n_vec)
{
    const int j = blockIdx.x * BLK + threadIdx.x;   // float4 index
    float s = 0.0f;
    int cnt = 0;
    if (j < n_vec) {
        const int c = cls[j >> 1];                  // anchor = j/2
        const float4 a = p4[j];                     // unit-stride across wave
        const float4 b = t4[j];
        const float v = sl1(a.x - b.x) + sl1(a.y - b.y)
                      + sl1(a.z - b.z) + sl1(a.w - b.w);
        s   = (c > 0) ? v : 0.0f;                   // branchless (cndmask)
        cnt = (c > 0) && ((j & 1) == 0);            // count each anchor once
    }
    // wave-64 reduce (f64 from here on; round-1 proved absmax 0.0 this way)
    double acc = (double)s;
    #pragma unroll
    for (int off = 32; off > 0; off >>= 1) {
        acc += __shfl_down(acc, off, 64);
        cnt += __shfl_down(cnt, off, 64);
    }
    __shared__ double ssum[BLK / 64];
    __shared__ int    scnt[BLK / 64];
    const int lane = threadIdx.x & 63;
    const int wid  = threadIdx.x >> 6;
    if (lane == 0) { ssum[wid] = acc; scnt[wid] = cnt; }
    __syncthreads();
    if (threadIdx.x == 0) {
        double a = 0.0; int c = 0;
        #pragma unroll
        for (int w = 0; w < BLK / 64; ++w) { a += ssum[w]; c += scnt[w]; }
        part_sum[blockIdx.x] = a;
        part_cnt[blockIdx.x] = c;
    }
}

__global__ __launch_bounds__(BLK) void ohem_final(
        const double* __restrict__ part_sum,
        const int*    __restrict__ part_cnt,
        float* __restrict__ out, int nblk)
{
    double acc = 0.0;
    long long cnt = 0;
    for (int i = threadIdx.x; i < nblk; i += BLK) {
        acc += part_sum[i];
        cnt += part_cnt[i];
    }
    #pragma unroll
    for (int off = 32; off > 0; off >>= 1) {
        acc += __shfl_down(acc, off, 64);
        cnt += __shfl_down(cnt, off, 64);
    }
    __shared__ double    ssum[BLK / 64];
    __shared__ long long scnt[BLK / 64];
    const int lane = threadIdx.x & 63;
    const int wid  = threadIdx.x >> 6;
    if (lane == 0) { ssum[wid] = acc; scnt[wid] = cnt; }
    __syncthreads();
    if (threadIdx.x == 0) {
        double a = 0.0; long long c = 0;
        #pragma unroll
        for (int w = 0; w < BLK / 64; ++w) { a += ssum[w]; c += scnt[w]; }
        out[0] = (float)(0.2 * a / (double)c);
    }
}

extern "C" void kernel_launch(void* const* d_in, const int* in_sizes, int n_in,
                              void* d_out, int out_size, void* d_ws, size_t ws_size,
                              hipStream_t stream) {
    const float4* p4  = (const float4*)d_in[0];   // [B, A, 8] f32 -> 2 float4/anchor
    const float4* t4  = (const float4*)d_in[1];
    // d_in[2] (cls_preds) provably unused: ce == 0 when C == 1.
    const int*    cls = (const int*)d_in[3];      // [B, A] i32
    const int n_anchor = in_sizes[3];             // B * A = 3,200,000
    const int n_vec    = n_anchor * 2;            // 6,400,000 float4 per array
    const int nblk     = (n_vec + BLK - 1) / BLK; // 25000, exact cover

    double* part_sum = (double*)d_ws;
    int*    part_cnt = (int*)((char*)d_ws + (size_t)nblk * sizeof(double));

    ohem_partial<<<nblk, BLK, 0, stream>>>(p4, t4, cls,
                                           part_sum, part_cnt, n_vec);
    ohem_final<<<1, BLK, 0, stream>>>(part_sum, part_cnt, (float*)d_out, nblk);
}